// Round 1
// baseline (573.289 us; speedup 1.0000x reference)
//
#include <hip/hip_runtime.h>
#include <hip/hip_bf16.h>
#include <cstdint>
#include <cstddef>

#define B_ 4
#define D_ 256
#define N_ 4096
#define N1 4097
#define MARGIN_ 0.5f
#define MAXD_ 10000.0f
#define BIGV_ 1000000000.0f

typedef short s8v __attribute__((ext_vector_type(8)));
typedef float f4v __attribute__((ext_vector_type(4)));

// Order-preserving float <-> uint encoding so atomicMax/atomicMin on uint == on float.
__device__ __forceinline__ unsigned enc_f(float f) {
    unsigned u = __float_as_uint(f);
    return (u & 0x80000000u) ? ~u : (u | 0x80000000u);
}
__device__ __forceinline__ float dec_f(unsigned e) {
    return (e & 0x80000000u) ? __uint_as_float(e & 0x7FFFFFFFu) : __uint_as_float(~e);
}

__device__ __forceinline__ void async_copy16(__hip_bfloat16* lds, const __hip_bfloat16* g) {
    __builtin_amdgcn_global_load_lds(
        (const __attribute__((address_space(1))) void*)g,
        (__attribute__((address_space(3))) void*)lds, 16, 0, 0);
}

// ---------------- init: pos enc = 0 (== -inf), mn enc = 0xFFFFFFFF (== +inf) -------------
__global__ void init_k(unsigned* __restrict__ p) {
    int i = blockIdx.x * 256 + threadIdx.x;
    if (i < 2 * B_ * N_) p[i] = 0u;
    else if (i < 4 * B_ * N_) p[i] = 0xFFFFFFFFu;
}

// ---------------- transpose+convert: (B,D,N) f32 -> (B,N,D) bf16 ----------------
__global__ __launch_bounds__(256) void transpose_k(const float* __restrict__ src,
                                                   __hip_bfloat16* __restrict__ dst) {
    __shared__ float tile[64][65];
    int b = blockIdx.z;
    int i0 = blockIdx.x * 64;   // n-dim
    int k0 = blockIdx.y * 64;   // d-dim
    int tx = threadIdx.x;       // 0..63
    int ty = threadIdx.y;       // 0..3
    const float* s = src + ((size_t)b * D_ + k0) * N_ + i0;
#pragma unroll
    for (int r = 0; r < 16; ++r) {
        int kk = ty + 4 * r;
        tile[kk][tx] = s[(size_t)kk * N_ + tx];
    }
    __syncthreads();
    __hip_bfloat16* d = dst + ((size_t)b * N_ + i0) * D_ + k0;
#pragma unroll
    for (int r = 0; r < 16; ++r) {
        int ii = ty + 4 * r;
        d[(size_t)ii * D_ + tx] = __float2bfloat16(tile[tx][ii]);
    }
}

// ---------------- fused GEMM + epilogue ----------------
// At, Bt: (B, N, D) bf16.  D[i][j] = 2 - 2*dot(At[i,:], Bt[j,:])
template <bool PASS2>
__global__ __launch_bounds__(256) void gemm_k(const __hip_bfloat16* __restrict__ At,
                                              const __hip_bfloat16* __restrict__ Bt,
                                              const float* __restrict__ mat,
                                              unsigned* __restrict__ pos0e,
                                              unsigned* __restrict__ pos1e,
                                              unsigned* __restrict__ mn0e,
                                              unsigned* __restrict__ mn1e) {
    __shared__ __align__(16) __hip_bfloat16 As[128 * 64];
    __shared__ __align__(16) __hip_bfloat16 Bs[128 * 64];
    __shared__ float sP0[128];
    __shared__ float sP1[128];

    const int b = blockIdx.z;
    const int i0 = blockIdx.y * 128;
    const int j0 = blockIdx.x * 128;
    const int tid = threadIdx.x;
    const int lane = tid & 63;
    const int w = tid >> 6;
    const int wi = (w & 1) * 64;
    const int wj = (w >> 1) * 64;
    const int r = lane & 15;    // MFMA n / A-row lane index
    const int q = lane >> 4;    // MFMA quad

    if (PASS2) {
        if (tid < 128) sP0[tid] = dec_f(pos0e[b * N_ + i0 + tid]);
        else           sP1[tid - 128] = dec_f(pos1e[b * N_ + j0 + tid - 128]);
    }

    f4v acc[4][4];
#pragma unroll
    for (int a = 0; a < 4; ++a)
#pragma unroll
        for (int c = 0; c < 4; ++c) acc[a][c] = (f4v){0.f, 0.f, 0.f, 0.f};

    const __hip_bfloat16* Ab = At + ((size_t)b * N_ + i0) * D_;
    const __hip_bfloat16* Bb = Bt + ((size_t)b * N_ + j0) * D_;

    const int row_in_chunk = lane >> 3;   // 0..7
    const int seg = lane & 7;             // 0..7 (8 bf16 = 16B per lane)

    for (int kt = 0; kt < 4; ++kt) {      // K tiles of 64 (D=256)
#pragma unroll
        for (int rd = 0; rd < 4; ++rd) {
            int c = rd * 4 + w;           // 16 chunks of 8 rows x 64 k
            const __hip_bfloat16* ga = Ab + (size_t)(c * 8 + row_in_chunk) * D_ + kt * 64 + seg * 8;
            async_copy16(&As[c * 512], ga);
            const __hip_bfloat16* gb = Bb + (size_t)(c * 8 + row_in_chunk) * D_ + kt * 64 + seg * 8;
            async_copy16(&Bs[c * 512], gb);
        }
        __syncthreads();
#pragma unroll
        for (int kk = 0; kk < 2; ++kk) {  // two k=32 steps
            s8v af[4], bf[4];
#pragma unroll
            for (int mi = 0; mi < 4; ++mi)
                af[mi] = *(const s8v*)&As[(wi + mi * 16 + r) * 64 + kk * 32 + q * 8];
#pragma unroll
            for (int nj = 0; nj < 4; ++nj)
                bf[nj] = *(const s8v*)&Bs[(wj + nj * 16 + r) * 64 + kk * 32 + q * 8];
#pragma unroll
            for (int mi = 0; mi < 4; ++mi)
#pragma unroll
                for (int nj = 0; nj < 4; ++nj)
                    acc[mi][nj] = __builtin_amdgcn_mfma_f32_16x16x32_bf16(af[mi], bf[nj], acc[mi][nj], 0, 0, 0);
        }
        __syncthreads();
    }

    // -------- epilogue --------
    // lane element (mi, nj, rr): i_loc = wi + mi*16 + q*4 + rr ; j_loc = wj + nj*16 + r
    const float* matb = mat + (size_t)b * N1 * N1 + (size_t)i0 * N1 + j0;

    if (!PASS2) {
        float rowmax[16];
        float colmax[4];
#pragma unroll
        for (int t = 0; t < 16; ++t) rowmax[t] = -BIGV_;
#pragma unroll
        for (int t = 0; t < 4; ++t) colmax[t] = -BIGV_;
#pragma unroll
        for (int mi = 0; mi < 4; ++mi) {
#pragma unroll
            for (int rr = 0; rr < 4; ++rr) {
                int il = wi + mi * 16 + q * 4 + rr;
                const float* row = matb + (size_t)il * N1 + wj;
#pragma unroll
                for (int nj = 0; nj < 4; ++nj) {
                    float ov = row[nj * 16 + r];
                    float Dv = 2.0f - 2.0f * acc[mi][nj][rr];
                    float dp = (ov > 0.3f) ? Dv : 0.0f;
                    rowmax[mi * 4 + rr] = fmaxf(rowmax[mi * 4 + rr], dp);
                    colmax[nj] = fmaxf(colmax[nj], dp);
                }
            }
        }
#pragma unroll
        for (int t = 0; t < 16; ++t) {
            float v = rowmax[t];
#pragma unroll
            for (int m = 1; m < 16; m <<= 1) v = fmaxf(v, __shfl_xor(v, m, 64));
            if (r == 0) {
                int i_g = i0 + wi + (t >> 2) * 16 + q * 4 + (t & 3);
                atomicMax(&pos0e[b * N_ + i_g], enc_f(v));
            }
        }
#pragma unroll
        for (int nj = 0; nj < 4; ++nj) {
            float v = colmax[nj];
            v = fmaxf(v, __shfl_xor(v, 16, 64));
            v = fmaxf(v, __shfl_xor(v, 32, 64));
            if (q == 0) {
                int j_g = j0 + wj + nj * 16 + r;
                atomicMax(&pos1e[b * N_ + j_g], enc_f(v));
            }
        }
    } else {
        float rowmin[16];
        float colmin[4];
        float p1v[4];
#pragma unroll
        for (int t = 0; t < 16; ++t) rowmin[t] = BIGV_;
#pragma unroll
        for (int t = 0; t < 4; ++t) colmin[t] = BIGV_;
#pragma unroll
        for (int nj = 0; nj < 4; ++nj) p1v[nj] = sP1[wj + nj * 16 + r];
#pragma unroll
        for (int mi = 0; mi < 4; ++mi) {
#pragma unroll
            for (int rr = 0; rr < 4; ++rr) {
                int il = wi + mi * 16 + q * 4 + rr;
                float p0 = sP0[il];
                const float* row = matb + (size_t)il * N1 + wj;
#pragma unroll
                for (int nj = 0; nj < 4; ++nj) {
                    float ov = row[nj * 16 + r];
                    float Dv = 2.0f - 2.0f * acc[mi][nj][rr];
                    float ng = (ov <= 0.0f) ? Dv : MAXD_;
                    float c0 = (ng > p0 && ng < p0 + MARGIN_) ? ng : BIGV_;
                    rowmin[mi * 4 + rr] = fminf(rowmin[mi * 4 + rr], c0);
                    float p1 = p1v[nj];
                    float c1 = (ng > p1 && ng < p1 + MARGIN_) ? ng : BIGV_;
                    colmin[nj] = fminf(colmin[nj], c1);
                }
            }
        }
#pragma unroll
        for (int t = 0; t < 16; ++t) {
            float v = rowmin[t];
#pragma unroll
            for (int m = 1; m < 16; m <<= 1) v = fminf(v, __shfl_xor(v, m, 64));
            if (r == 0) {
                int i_g = i0 + wi + (t >> 2) * 16 + q * 4 + (t & 3);
                atomicMin(&mn0e[b * N_ + i_g], enc_f(v));
            }
        }
#pragma unroll
        for (int nj = 0; nj < 4; ++nj) {
            float v = colmin[nj];
            v = fminf(v, __shfl_xor(v, 16, 64));
            v = fminf(v, __shfl_xor(v, 32, 64));
            if (q == 0) {
                int j_g = j0 + wj + nj * 16 + r;
                atomicMin(&mn1e[b * N_ + j_g], enc_f(v));
            }
        }
    }
}

// ---------------- final reduce: 2*B*N (pos, mn) pairs -> 3 outputs ----------------
__global__ __launch_bounds__(1024) void reduce_k(const unsigned* __restrict__ pose,
                                                 const unsigned* __restrict__ mne,
                                                 float* __restrict__ out) {
    int tid = threadIdx.x;
    float sum = 0.0f, cnt = 0.0f, hp = -BIGV_, hn = BIGV_;
    for (int idx = tid; idx < 2 * B_ * N_; idx += 1024) {
        float pos = dec_f(pose[idx]);
        float mn = dec_f(mne[idx]);
        bool valid = (pos > 0.0f) && (mn < 1.0e8f);
        if (valid) {
            sum += fmaxf(pos - mn + 1.0f, 0.0f);
            cnt += 1.0f;
            hp = fmaxf(hp, pos);
            hn = fminf(hn, mn);
        }
    }
#pragma unroll
    for (int m = 1; m < 64; m <<= 1) {
        sum += __shfl_xor(sum, m, 64);
        cnt += __shfl_xor(cnt, m, 64);
        hp = fmaxf(hp, __shfl_xor(hp, m, 64));
        hn = fminf(hn, __shfl_xor(hn, m, 64));
    }
    __shared__ float ssum[16], scnt[16], shp[16], shn[16];
    int wv = tid >> 6;
    if ((tid & 63) == 0) { ssum[wv] = sum; scnt[wv] = cnt; shp[wv] = hp; shn[wv] = hn; }
    __syncthreads();
    if (tid == 0) {
        float S = 0.f, C = 0.f, P = -BIGV_, M = BIGV_;
#pragma unroll
        for (int i = 0; i < 16; ++i) {
            S += ssum[i]; C += scnt[i];
            P = fmaxf(P, shp[i]); M = fminf(M, shn[i]);
        }
        out[0] = S / fmaxf(C, 1.0f);
        out[1] = P;
        out[2] = M;
    }
}

extern "C" void kernel_launch(void* const* d_in, const int* in_sizes, int n_in,
                              void* d_out, int out_size, void* d_ws, size_t ws_size,
                              hipStream_t stream) {
    const float* desc0 = (const float*)d_in[0];
    const float* desc1 = (const float*)d_in[1];
    const float* mat = (const float*)d_in[2];
    float* out = (float*)d_out;

    // ws layout: [pos0|pos1] (2*B*N u32), [mn0|mn1] (2*B*N u32), At bf16, Bt bf16
    unsigned* pos = (unsigned*)d_ws;
    unsigned* mns = pos + 2 * B_ * N_;
    __hip_bfloat16* at = (__hip_bfloat16*)(mns + 2 * B_ * N_);
    __hip_bfloat16* bt = at + (size_t)B_ * N_ * D_;

    init_k<<<(4 * B_ * N_ + 255) / 256, 256, 0, stream>>>(pos);
    transpose_k<<<dim3(N_ / 64, D_ / 64, B_), dim3(64, 4), 0, stream>>>(desc0, at);
    transpose_k<<<dim3(N_ / 64, D_ / 64, B_), dim3(64, 4), 0, stream>>>(desc1, bt);
    gemm_k<false><<<dim3(N_ / 128, N_ / 128, B_), 256, 0, stream>>>(
        at, bt, mat, pos, pos + B_ * N_, mns, mns + B_ * N_);
    gemm_k<true><<<dim3(N_ / 128, N_ / 128, B_), 256, 0, stream>>>(
        at, bt, mat, pos, pos + B_ * N_, mns, mns + B_ * N_);
    reduce_k<<<1, 1024, 0, stream>>>(pos, mns, out);
}

// Round 2
// 557.016 us; speedup vs baseline: 1.0292x; 1.0292x over previous
//
#include <hip/hip_runtime.h>
#include <hip/hip_bf16.h>
#include <cstdint>
#include <cstddef>

#define B_ 4
#define D_ 256
#define N_ 4096
#define N1 4097
#define MARGIN_ 0.5f
#define MAXD_ 10000.0f
#define BIGV_ 1000000000.0f

typedef short s8v __attribute__((ext_vector_type(8)));
typedef float f4v __attribute__((ext_vector_type(4)));
typedef _Float16 h8v __attribute__((ext_vector_type(8)));

// Order-preserving float <-> uint encoding so atomicMax/atomicMin on uint == on float.
__device__ __forceinline__ unsigned enc_f(float f) {
    unsigned u = __float_as_uint(f);
    return (u & 0x80000000u) ? ~u : (u | 0x80000000u);
}
__device__ __forceinline__ float dec_f(unsigned e) {
    return (e & 0x80000000u) ? __uint_as_float(e & 0x7FFFFFFFu) : __uint_as_float(~e);
}

__device__ __forceinline__ void async_copy16(__hip_bfloat16* lds, const __hip_bfloat16* g) {
    __builtin_amdgcn_global_load_lds(
        (const __attribute__((address_space(1))) void*)g,
        (__attribute__((address_space(3))) void*)lds, 16, 0, 0);
}

// ---------------- init: pos enc = 0 (== -inf), mn enc = 0xFFFFFFFF (== +inf) -------------
__global__ void init_k(unsigned* __restrict__ p) {
    int i = blockIdx.x * 256 + threadIdx.x;
    if (i < 2 * B_ * N_) p[i] = 0u;
    else if (i < 4 * B_ * N_) p[i] = 0xFFFFFFFFu;
}

// ---------------- transpose+convert: (B,D,N) f32 -> (B,N,D) bf16 ----------------
__global__ __launch_bounds__(256) void transpose_k(const float* __restrict__ src,
                                                   __hip_bfloat16* __restrict__ dst) {
    __shared__ float tile[64][65];
    int b = blockIdx.z;
    int i0 = blockIdx.x * 64;   // n-dim
    int k0 = blockIdx.y * 64;   // d-dim
    int tx = threadIdx.x;       // 0..63
    int ty = threadIdx.y;       // 0..3
    const float* s = src + ((size_t)b * D_ + k0) * N_ + i0;
#pragma unroll
    for (int r = 0; r < 16; ++r) {
        int kk = ty + 4 * r;
        tile[kk][tx] = s[(size_t)kk * N_ + tx];
    }
    __syncthreads();
    __hip_bfloat16* d = dst + ((size_t)b * N_ + i0) * D_ + k0;
#pragma unroll
    for (int r = 0; r < 16; ++r) {
        int ii = ty + 4 * r;
        d[(size_t)ii * D_ + tx] = __float2bfloat16(tile[tx][ii]);
    }
}

// ---------------- fused GEMM pass: pos maxes + neg (fp16) materialization ----------------
// At, Bt: (B, N, D) bf16.  dist[i][j] = 2 - 2*dot(At[i,:], Bt[j,:])
// LDS layout is XOR-swizzled: slot (row, seg) holds global seg (seg ^ (row&7)).
__global__ __launch_bounds__(256) void gemm_k(const __hip_bfloat16* __restrict__ At,
                                              const __hip_bfloat16* __restrict__ Bt,
                                              const float* __restrict__ mat,
                                              unsigned* __restrict__ pos0e,
                                              unsigned* __restrict__ pos1e,
                                              _Float16* __restrict__ neg) {
    __shared__ __align__(16) __hip_bfloat16 As[128 * 64];
    __shared__ __align__(16) __hip_bfloat16 Bs[128 * 64];

    const int b = blockIdx.z;
    const int i0 = blockIdx.y * 128;
    const int j0 = blockIdx.x * 128;
    const int tid = threadIdx.x;
    const int lane = tid & 63;
    const int w = tid >> 6;
    const int wi = (w & 1) * 64;
    const int wj = (w >> 1) * 64;
    const int r = lane & 15;    // MFMA col lane index
    const int q = lane >> 4;    // MFMA quad

    f4v acc[4][4];
#pragma unroll
    for (int a = 0; a < 4; ++a)
#pragma unroll
        for (int c = 0; c < 4; ++c) acc[a][c] = (f4v){0.f, 0.f, 0.f, 0.f};

    const __hip_bfloat16* Ab = At + ((size_t)b * N_ + i0) * D_;
    const __hip_bfloat16* Bb = Bt + ((size_t)b * N_ + j0) * D_;

    const int row_in_chunk = lane >> 3;               // 0..7
    const int seg = lane & 7;                         // 0..7 (8 bf16 = 16B)
    const int segg = seg ^ row_in_chunk;              // XOR-swizzled source seg

    for (int kt = 0; kt < 4; ++kt) {      // K tiles of 64 (D=256)
#pragma unroll
        for (int rd = 0; rd < 4; ++rd) {
            int c = rd * 4 + w;           // 16 chunks of 8 rows x 64 k
            const __hip_bfloat16* ga = Ab + (size_t)(c * 8 + row_in_chunk) * D_ + kt * 64 + segg * 8;
            async_copy16(&As[c * 512], ga);
            const __hip_bfloat16* gb = Bb + (size_t)(c * 8 + row_in_chunk) * D_ + kt * 64 + segg * 8;
            async_copy16(&Bs[c * 512], gb);
        }
        __syncthreads();
#pragma unroll
        for (int kk = 0; kk < 2; ++kk) {  // two k=32 steps
            s8v af[4], bf[4];
#pragma unroll
            for (int mi = 0; mi < 4; ++mi) {
                int rowA = wi + mi * 16 + r;
                af[mi] = *(const s8v*)&As[rowA * 64 + ((kk * 4 + q) ^ (rowA & 7)) * 8];
            }
#pragma unroll
            for (int nj = 0; nj < 4; ++nj) {
                int rowB = wj + nj * 16 + r;
                bf[nj] = *(const s8v*)&Bs[rowB * 64 + ((kk * 4 + q) ^ (rowB & 7)) * 8];
            }
#pragma unroll
            for (int mi = 0; mi < 4; ++mi)
#pragma unroll
                for (int nj = 0; nj < 4; ++nj)
                    acc[mi][nj] = __builtin_amdgcn_mfma_f32_16x16x32_bf16(af[mi], bf[nj], acc[mi][nj], 0, 0, 0);
        }
        __syncthreads();
    }

    // -------- epilogue: pos row/col maxes + neg store --------
    // lane element (mi, nj, rr): i_loc = wi + mi*16 + q*4 + rr ; j_loc = wj + nj*16 + r
    const float* matb = mat + (size_t)b * N1 * N1 + (size_t)i0 * N1 + j0;
    _Float16* negb = neg + ((size_t)b * N_ + i0) * N_ + j0;

    float rowmax[16];
    float colmax[4];
#pragma unroll
    for (int t = 0; t < 16; ++t) rowmax[t] = -BIGV_;
#pragma unroll
    for (int t = 0; t < 4; ++t) colmax[t] = -BIGV_;
#pragma unroll
    for (int mi = 0; mi < 4; ++mi) {
#pragma unroll
        for (int rr = 0; rr < 4; ++rr) {
            int il = wi + mi * 16 + q * 4 + rr;
            const float* row = matb + (size_t)il * N1 + wj;
            _Float16* nrow = negb + (size_t)il * N_ + wj;
#pragma unroll
            for (int nj = 0; nj < 4; ++nj) {
                float ov = row[nj * 16 + r];
                float Dv = 2.0f - 2.0f * acc[mi][nj][rr];
                float dp = (ov > 0.3f) ? Dv : 0.0f;
                rowmax[mi * 4 + rr] = fmaxf(rowmax[mi * 4 + rr], dp);
                colmax[nj] = fmaxf(colmax[nj], dp);
                float ng = (ov <= 0.0f) ? Dv : MAXD_;
                nrow[nj * 16 + r] = (_Float16)ng;
            }
        }
    }
#pragma unroll
    for (int t = 0; t < 16; ++t) {
        float v = rowmax[t];
#pragma unroll
        for (int m = 1; m < 16; m <<= 1) v = fmaxf(v, __shfl_xor(v, m, 64));
        if (r == 0) {
            int i_g = i0 + wi + (t >> 2) * 16 + q * 4 + (t & 3);
            atomicMax(&pos0e[b * N_ + i_g], enc_f(v));
        }
    }
#pragma unroll
    for (int nj = 0; nj < 4; ++nj) {
        float v = colmax[nj];
        v = fmaxf(v, __shfl_xor(v, 16, 64));
        v = fmaxf(v, __shfl_xor(v, 32, 64));
        if (q == 0) {
            int j_g = j0 + wj + nj * 16 + r;
            atomicMax(&pos1e[b * N_ + j_g], enc_f(v));
        }
    }
}

// ---------------- pass 2: stream neg, masked mins vs pos0/pos1 ----------------
// grid: (N/64 row-stripes, B). Each block owns 64 full rows -> mn0 plain store.
__global__ __launch_bounds__(256) void neg_scan_k(const _Float16* __restrict__ neg,
                                                  const unsigned* __restrict__ pos0e,
                                                  const unsigned* __restrict__ pos1e,
                                                  unsigned* __restrict__ mn0e,
                                                  unsigned* __restrict__ mn1e) {
    __shared__ float sP0[64];
    __shared__ float sR[64][4];
    const int b = blockIdx.y;
    const int i0 = blockIdx.x * 64;
    const int tid = threadIdx.x;
    const int w = tid >> 6;
    const int lane = tid & 63;
    if (tid < 64) sP0[tid] = dec_f(pos0e[b * N_ + i0 + tid]);
    float p1[16], cm[16];
#pragma unroll
    for (int h = 0; h < 2; ++h)
#pragma unroll
        for (int k = 0; k < 8; ++k) {
            int cidx = h * 2048 + tid * 8 + k;
            p1[h * 8 + k] = dec_f(pos1e[b * N_ + cidx]);
            cm[h * 8 + k] = BIGV_;
        }
    __syncthreads();
    const _Float16* nb = neg + ((size_t)b * N_ + i0) * N_;
    for (int r = 0; r < 64; ++r) {
        float p0 = sP0[r];
        float rmin = BIGV_;
#pragma unroll
        for (int h = 0; h < 2; ++h) {
            h8v v = *(const h8v*)&nb[(size_t)r * N_ + h * 2048 + tid * 8];
#pragma unroll
            for (int k = 0; k < 8; ++k) {
                float ng = (float)v[k];
                float c0 = (ng > p0 && ng < p0 + MARGIN_) ? ng : BIGV_;
                rmin = fminf(rmin, c0);
                float pv = p1[h * 8 + k];
                float c1 = (ng > pv && ng < pv + MARGIN_) ? ng : BIGV_;
                cm[h * 8 + k] = fminf(cm[h * 8 + k], c1);
            }
        }
#pragma unroll
        for (int m = 1; m < 64; m <<= 1) rmin = fminf(rmin, __shfl_xor(rmin, m, 64));
        if (lane == 0) sR[r][w] = rmin;
    }
    __syncthreads();
    if (tid < 64) {
        float m = fminf(fminf(sR[tid][0], sR[tid][1]), fminf(sR[tid][2], sR[tid][3]));
        mn0e[b * N_ + i0 + tid] = enc_f(m);   // exclusive owner of these rows
    }
#pragma unroll
    for (int h = 0; h < 2; ++h)
#pragma unroll
        for (int k = 0; k < 8; ++k)
            atomicMin(&mn1e[b * N_ + h * 2048 + tid * 8 + k], enc_f(cm[h * 8 + k]));
}

// ---------------- final reduce: 2*B*N (pos, mn) pairs -> 3 outputs ----------------
__global__ __launch_bounds__(1024) void reduce_k(const unsigned* __restrict__ pose,
                                                 const unsigned* __restrict__ mne,
                                                 float* __restrict__ out) {
    int tid = threadIdx.x;
    float sum = 0.0f, cnt = 0.0f, hp = -BIGV_, hn = BIGV_;
    for (int idx = tid; idx < 2 * B_ * N_; idx += 1024) {
        float pos = dec_f(pose[idx]);
        float mn = dec_f(mne[idx]);
        bool valid = (pos > 0.0f) && (mn < 1.0e8f);
        if (valid) {
            sum += fmaxf(pos - mn + 1.0f, 0.0f);
            cnt += 1.0f;
            hp = fmaxf(hp, pos);
            hn = fminf(hn, mn);
        }
    }
#pragma unroll
    for (int m = 1; m < 64; m <<= 1) {
        sum += __shfl_xor(sum, m, 64);
        cnt += __shfl_xor(cnt, m, 64);
        hp = fmaxf(hp, __shfl_xor(hp, m, 64));
        hn = fminf(hn, __shfl_xor(hn, m, 64));
    }
    __shared__ float ssum[16], scnt[16], shp[16], shn[16];
    int wv = tid >> 6;
    if ((tid & 63) == 0) { ssum[wv] = sum; scnt[wv] = cnt; shp[wv] = hp; shn[wv] = hn; }
    __syncthreads();
    if (tid == 0) {
        float S = 0.f, C = 0.f, P = -BIGV_, M = BIGV_;
#pragma unroll
        for (int i = 0; i < 16; ++i) {
            S += ssum[i]; C += scnt[i];
            P = fmaxf(P, shp[i]); M = fminf(M, shn[i]);
        }
        out[0] = S / fmaxf(C, 1.0f);
        out[1] = P;
        out[2] = M;
    }
}

extern "C" void kernel_launch(void* const* d_in, const int* in_sizes, int n_in,
                              void* d_out, int out_size, void* d_ws, size_t ws_size,
                              hipStream_t stream) {
    const float* desc0 = (const float*)d_in[0];
    const float* desc1 = (const float*)d_in[1];
    const float* mat = (const float*)d_in[2];
    float* out = (float*)d_out;

    // ws layout: [pos0|pos1] (2*B*N u32), [mn0|mn1] (2*B*N u32), At bf16, Bt bf16, neg fp16
    unsigned* pos = (unsigned*)d_ws;
    unsigned* mns = pos + 2 * B_ * N_;
    __hip_bfloat16* at = (__hip_bfloat16*)(mns + 2 * B_ * N_);
    __hip_bfloat16* bt = at + (size_t)B_ * N_ * D_;
    _Float16* neg = (_Float16*)(bt + (size_t)B_ * N_ * D_);

    init_k<<<(4 * B_ * N_ + 255) / 256, 256, 0, stream>>>(pos);
    transpose_k<<<dim3(N_ / 64, D_ / 64, B_), dim3(64, 4), 0, stream>>>(desc0, at);
    transpose_k<<<dim3(N_ / 64, D_ / 64, B_), dim3(64, 4), 0, stream>>>(desc1, bt);
    gemm_k<<<dim3(N_ / 128, N_ / 128, B_), 256, 0, stream>>>(
        at, bt, mat, pos, pos + B_ * N_, neg);
    neg_scan_k<<<dim3(N_ / 64, B_), 256, 0, stream>>>(
        neg, pos, pos + B_ * N_, mns, mns + B_ * N_);
    reduce_k<<<1, 1024, 0, stream>>>(pos, mns, out);
}